// Round 11
// baseline (349.073 us; speedup 1.0000x reference)
//
#include <hip/hip_runtime.h>
#include <hip/hip_bf16.h>
#include <math.h>

#define B_ 4
#define N_ 1024
#define D_ 1024
#define E_ 8
#define H_ 2730
#define H2_ 5460
#define CAP_ 256
#define NTOK 4096
#define NSLOT 8192
#define NKT1 16      // packing K-tiles (BK=64) for GEMM1 buffers
#define NK1T 32      // ffn1 compute K-tiles (BK=32)
#define NKT2 43      // packing K-tiles (BK=64) for GEMM2
#define NK2T 86      // ffn2 compute K-tiles (BK=32)
#define NFG 22       // 128-wide f-col groups (pad 2816)

typedef __attribute__((ext_vector_type(8))) short short8;
typedef __attribute__((ext_vector_type(4))) float f32x4;

__device__ __forceinline__ unsigned short f2bf(float f) {
    __hip_bfloat16 h = __float2bfloat16(f);
    return *reinterpret_cast<unsigned short*>(&h);
}
__device__ __forceinline__ float bf2f(unsigned short u) {
    unsigned x = ((unsigned)u) << 16;
    union { unsigned u; float f; } c; c.u = x; return c.f;
}

// async global(16B/lane) -> LDS (wave-uniform base + lane*16)
#define GLL16(g, l)                                                          \
    __builtin_amdgcn_global_load_lds(                                        \
        (const __attribute__((address_space(1))) void*)(g),                  \
        (__attribute__((address_space(3))) void*)(l), 16, 0, 0)

#define VMCNT0() asm volatile("s_waitcnt vmcnt(0)" ::: "memory")
#define VMW8()   asm volatile("s_waitcnt vmcnt(8)" ::: "memory")
#define LGKM0()  asm volatile("s_waitcnt lgkmcnt(0)" ::: "memory")
#define SCHEDB() __builtin_amdgcn_sched_barrier(0)
#define MFMA16(a, b, c) __builtin_amdgcn_mfma_f32_16x16x32_bf16((a), (b), (c), 0, 0, 0)

// ============ fragment-packed layouts (bytes unchanged from r5) ============
// A chunk (per (sgrp,kt64), 16384 ush): off = k32*8192 + m16*512 + lane*8 + b
// B1 chunk (per (e,fg,kt64), 16384 ush): off = k32*8192 + n16*512 + lane*8 + b ; n16 0..7 val, 8..15 gate
// B2 chunk (per (e,nt,kt64), 8192 ush): off = k32*4096 + n16*512 + lane*8 + b

// ---------------- cvt1 ----------------
__global__ __launch_bounds__(256) void k_cvt1(const float* __restrict__ w1,
                                              unsigned short* __restrict__ w1p) {
    const int fg = blockIdx.x;   // 0..21
    const int kt = blockIdx.y;   // 0..15
    const int e  = blockIdx.z;
    const float* w1e = w1 + (size_t)e * D_ * H2_;
    unsigned short* dst = w1p + (((size_t)((e * NFG + fg) * NKT1 + kt)) << 14);
#pragma unroll
    for (int i = 0; i < 8; ++i) {
        const int o = i * 256 + threadIdx.x;
        const int l = o & 63, n16 = (o >> 6) & 15, k32 = o >> 10;
        const int f = fg * 128 + ((n16 & 7) << 4) + (l & 15);
        const int k = kt * 64 + (k32 << 5) + ((l >> 4) << 3);
        ushort4 r0 = {0, 0, 0, 0}, r1 = {0, 0, 0, 0};
        if (f < H_) {
            const float* s = w1e + (size_t)k * H2_ + (n16 >= 8 ? H_ : 0) + f;
            r0.x = f2bf(s[0]);
            r0.y = f2bf(s[(size_t)H2_]);
            r0.z = f2bf(s[(size_t)2 * H2_]);
            r0.w = f2bf(s[(size_t)3 * H2_]);
            r1.x = f2bf(s[(size_t)4 * H2_]);
            r1.y = f2bf(s[(size_t)5 * H2_]);
            r1.z = f2bf(s[(size_t)6 * H2_]);
            r1.w = f2bf(s[(size_t)7 * H2_]);
        }
        *reinterpret_cast<ushort4*>(dst + (size_t)o * 8) = r0;
        *reinterpret_cast<ushort4*>(dst + (size_t)o * 8 + 4) = r1;
    }
}

// ---------------- cvt2 ----------------
__global__ __launch_bounds__(256) void k_cvt2(const float* __restrict__ w2,
                                              unsigned short* __restrict__ w2p) {
    const int kt = blockIdx.x;   // 0..42
    const int nt = blockIdx.y;   // 0..7
    const int e  = blockIdx.z;
    const float* w2e = w2 + (size_t)e * H_ * D_;
    unsigned short* dst = w2p + (((size_t)((e * 8 + nt) * NKT2 + kt)) << 13);
#pragma unroll
    for (int i = 0; i < 4; ++i) {
        const int o = i * 256 + threadIdx.x;
        const int l = o & 63, n16 = (o >> 6) & 7, k32 = o >> 9;
        const int d = nt * 128 + (n16 << 4) + (l & 15);
        const int f = kt * 64 + (k32 << 5) + ((l >> 4) << 3);
        const float* s = w2e + (size_t)f * D_ + d;
        ushort4 r0, r1;
        r0.x = (f + 0 < H_) ? f2bf(s[0]) : 0;
        r0.y = (f + 1 < H_) ? f2bf(s[(size_t)D_]) : 0;
        r0.z = (f + 2 < H_) ? f2bf(s[(size_t)2 * D_]) : 0;
        r0.w = (f + 3 < H_) ? f2bf(s[(size_t)3 * D_]) : 0;
        r1.x = (f + 4 < H_) ? f2bf(s[(size_t)4 * D_]) : 0;
        r1.y = (f + 5 < H_) ? f2bf(s[(size_t)5 * D_]) : 0;
        r1.z = (f + 6 < H_) ? f2bf(s[(size_t)6 * D_]) : 0;
        r1.w = (f + 7 < H_) ? f2bf(s[(size_t)7 * D_]) : 0;
        *reinterpret_cast<ushort4*>(dst + (size_t)o * 8) = r0;
        *reinterpret_cast<ushort4*>(dst + (size_t)o * 8 + 4) = r1;
    }
}

// ---------------- gating ----------------
__global__ __launch_bounds__(256) void k_gate(const float* __restrict__ x,
                                              const float* __restrict__ route,
                                              const float* __restrict__ gw,
                                              int* __restrict__ tokE,
                                              float* __restrict__ tokG,
                                              int* __restrict__ tokR) {
    const int wave = threadIdx.x >> 6, lane = threadIdx.x & 63;
    const int t = blockIdx.x * 4 + wave;
    float acc[E_];
#pragma unroll
    for (int e = 0; e < E_; ++e) acc[e] = 0.f;
    const float* xr = x + (size_t)t * D_;
    for (int d = lane; d < D_; d += 64) {
        float xv = xr[d];
        const float* g = gw + d * E_;
#pragma unroll
        for (int e = 0; e < E_; ++e) acc[e] = fmaf(xv, g[e], acc[e]);
    }
#pragma unroll
    for (int e = 0; e < E_; ++e) {
#pragma unroll
        for (int off = 32; off; off >>= 1) acc[e] += __shfl_xor(acc[e], off);
    }
    if (lane == 0) {
        float m = acc[0];
#pragma unroll
        for (int e = 1; e < E_; ++e) m = fmaxf(m, acc[e]);
        float p[E_]; float s = 0.f;
#pragma unroll
        for (int e = 0; e < E_; ++e) { p[e] = expf(acc[e] - m); s += p[e]; }
        int i0 = 0; float v0 = p[0];
#pragma unroll
        for (int e = 1; e < E_; ++e) if (p[e] > v0) { v0 = p[e]; i0 = e; }
        int i1 = (i0 == 0) ? 1 : 0; float v1 = p[i1];
#pragma unroll
        for (int e = 0; e < E_; ++e) if (e != i0 && p[e] > v1) { v1 = p[e]; i1 = e; }
        float p0 = v0 / s, p1 = v1 / s;
        float denom = fmaxf(p0 + p1, 1e-9f);
        float g0 = p0 / denom, g1 = p1 / denom;
        int r1 = route[NTOK + t] < (g1 / 0.2f);
        tokE[t] = i0; tokE[NTOK + t] = i1;
        tokG[t] = g0; tokG[NTOK + t] = g1;
        tokR[t] = r1;
    }
}

// ---------------- positions ----------------
__global__ __launch_bounds__(256) void k_pos(const int* __restrict__ tokE,
                                             const float* __restrict__ tokG,
                                             const int* __restrict__ tokR,
                                             int* __restrict__ sot,
                                             int* __restrict__ tos) {
    const int e = blockIdx.x & 7, b = blockIdx.x >> 3;
    const int t = threadIdx.x;
    __shared__ int sc[256];
    const int base_bt = b * N_ + t * 4;
    int m0[4], m1[4];
    int c0 = 0, c1 = 0;
#pragma unroll
    for (int i = 0; i < 4; ++i) {
        int bt = base_bt + i;
        m0[i] = (tokE[bt] == e) ? 1 : 0;
        m1[i] = ((tokE[NTOK + bt] == e) && tokR[bt]) ? 1 : 0;
        c0 += m0[i]; c1 += m1[i];
    }
    int packed = c0 | (c1 << 16);
    sc[t] = packed;
    __syncthreads();
    for (int off = 1; off < 256; off <<= 1) {
        int v = (t >= off) ? sc[t - off] : 0;
        __syncthreads();
        sc[t] += v;
        __syncthreads();
    }
    int incl = sc[t];
    int total = sc[255];
    int excl = incl - packed;
    int base0 = excl & 0xffff;
    int base1 = excl >> 16;
    int kept0 = min(total & 0xffff, CAP_);
#pragma unroll
    for (int i = 0; i < 4; ++i) {
        int bt = base_bt + i;
        if (m0[i]) {
            int pos = base0++;
            if (pos < CAP_ && tokG[bt] > 0.f) {
                int s = ((e * B_ + b) << 8) + pos;
                sot[bt] = s;
                tos[s] = bt;
            }
        }
        if (m1[i]) {
            int pos = (base1++) + kept0;
            if (pos < CAP_ && tokG[NTOK + bt] > 0.f) {
                int s = ((e * B_ + b) << 8) + pos;
                sot[NTOK + bt] = s;
                tos[s] = bt;
            }
        }
    }
}

// ---------------- dispatch ----------------
__global__ __launch_bounds__(256) void k_disp(const float* __restrict__ x,
                                              const int* __restrict__ tos,
                                              unsigned short* __restrict__ xeP) {
    const int t = threadIdx.x;
    const int s = blockIdx.x * 2 + (t >> 7);
    const int q = t & 127;
    const int bt = tos[s];
    const int kt = q >> 3, k32 = (q >> 2) & 1, kq = q & 3;
    const int lane = (kq << 4) | (s & 15);
    const int m16 = (s >> 4) & 15;
    const int sgrp = s >> 8;
    unsigned short* dst = xeP + (((size_t)(sgrp * NKT1 + kt)) << 14) + (k32 << 13) + (m16 << 9) + lane * 8;
    ushort4 r0 = {0, 0, 0, 0}, r1 = {0, 0, 0, 0};
    if (bt >= 0) {
        const float4 v0 = *reinterpret_cast<const float4*>(x + ((size_t)bt << 10) + q * 8);
        const float4 v1 = *reinterpret_cast<const float4*>(x + ((size_t)bt << 10) + q * 8 + 4);
        r0.x = f2bf(v0.x); r0.y = f2bf(v0.y); r0.z = f2bf(v0.z); r0.w = f2bf(v0.w);
        r1.x = f2bf(v1.x); r1.y = f2bf(v1.y); r1.z = f2bf(v1.z); r1.w = f2bf(v1.w);
    }
    *reinterpret_cast<ushort4*>(dst) = r0;
    *reinterpret_cast<ushort4*>(dst + 4) = r1;
}

// per-tile ush offset within an A-chunk stream (BK=32 view)
#define AOFF(t) (((size_t)((t) >> 1) << 14) + (size_t)(((t) & 1) * 8192))
#define BOFF2(t) (((size_t)((t) >> 1) << 13) + (size_t)(((t) & 1) * 4096))

// ---------------- GEMM1 + GEGLU: 1-wave blocks, barrier-free, per-wave counted pipeline ----------------
// wave tile: 64 rows x 32 f x {val,gate}; BK=32; LDS 16KB (A/B x dbuf); no __syncthreads anywhere
#define F1T(ABUF, BBUF, KTN, LAST, PF)                                        \
    do {                                                                      \
        if (LAST) { VMCNT0(); } else { VMW8(); }                              \
        SCHEDB();                                                             \
        short8 a0, a1, a2, a3, v0, v1, g0, g1;                                \
        a0 = *(const short8*)&ABUF[lane8];                                    \
        a1 = *(const short8*)&ABUF[512 + lane8];                              \
        a2 = *(const short8*)&ABUF[1024 + lane8];                             \
        a3 = *(const short8*)&ABUF[1536 + lane8];                             \
        v0 = *(const short8*)&BBUF[lane8];                                    \
        v1 = *(const short8*)&BBUF[512 + lane8];                              \
        g0 = *(const short8*)&BBUF[1024 + lane8];                             \
        g1 = *(const short8*)&BBUF[1536 + lane8];                             \
        LGKM0(); SCHEDB();                                                    \
        if (PF) {                                                             \
            const unsigned short* as = abase + AOFF(KTN);                     \
            const unsigned short* bs = bbase + AOFF(KTN);                     \
            GLL16(as + lane8, (char*)&ABUF[0]);                               \
            GLL16(as + 512 + lane8, (char*)&ABUF[512]);                       \
            GLL16(as + 1024 + lane8, (char*)&ABUF[1024]);                     \
            GLL16(as + 1536 + lane8, (char*)&ABUF[1536]);                     \
            GLL16(bs + lane8, (char*)&BBUF[0]);                               \
            GLL16(bs + 512 + lane8, (char*)&BBUF[512]);                       \
            GLL16(bs + 4096 + lane8, (char*)&BBUF[1024]);                     \
            GLL16(bs + 4608 + lane8, (char*)&BBUF[1536]);                     \
        }                                                                     \
        __builtin_amdgcn_s_setprio(1);                                        \
        acc[0][0]=MFMA16(a0,v0,acc[0][0]); acc[0][1]=MFMA16(a0,v1,acc[0][1]); \
        acc[0][2]=MFMA16(a0,g0,acc[0][2]); acc[0][3]=MFMA16(a0,g1,acc[0][3]); \
        acc[1][0]=MFMA16(a1,v0,acc[1][0]); acc[1][1]=MFMA16(a1,v1,acc[1][1]); \
        acc[1][2]=MFMA16(a1,g0,acc[1][2]); acc[1][3]=MFMA16(a1,g1,acc[1][3]); \
        acc[2][0]=MFMA16(a2,v0,acc[2][0]); acc[2][1]=MFMA16(a2,v1,acc[2][1]); \
        acc[2][2]=MFMA16(a2,g0,acc[2][2]); acc[2][3]=MFMA16(a2,g1,acc[2][3]); \
        acc[3][0]=MFMA16(a3,v0,acc[3][0]); acc[3][1]=MFMA16(a3,v1,acc[3][1]); \
        acc[3][2]=MFMA16(a3,g0,acc[3][2]); acc[3][3]=MFMA16(a3,g1,acc[3][3]); \
        __builtin_amdgcn_s_setprio(0);                                        \
    } while (0)

__global__ __launch_bounds__(64) void k_ffn1(const unsigned short* __restrict__ xeP,
                                             const unsigned short* __restrict__ w1p,
                                             const float* __restrict__ b1,
                                             const float* __restrict__ mbias,
                                             unsigned short* __restrict__ actP) {
    const int wg = blockIdx.x;               // 11008 = 8 XCD * 1376
    const int e = wg & 7;                    // expert per XCD
    const int rem = wg >> 3;                 // 0..1375
    const int fh = rem >> 4;                 // 0..85 (32-f blocks; 16 rb share B panel)
    const int rb = rem & 15;                 // 0..15 (64-row blocks)
    const int sgrp = e * 4 + (rb >> 2);
    const int m16b = (rb & 3) * 4;
    const int fg = fh >> 2;
    const int n16v = (fh & 3) * 2;

    __shared__ unsigned short A0[2048];
    __shared__ unsigned short B0[2048];
    __shared__ unsigned short A1[2048];
    __shared__ unsigned short B1[2048];      // 16 KB -> 10 blocks/CU

    const int lane = threadIdx.x;            // 0..63
    const int lane8 = lane * 8;

    const unsigned short* abase = xeP + ((size_t)(sgrp * NKT1) << 14) + m16b * 512;
    const unsigned short* bbase = w1p + ((size_t)((e * NFG + fg) * NKT1) << 14) + n16v * 512;

    f32x4 acc[4][4];   // [mi][v0,v1,g0,g1]
#pragma unroll
    for (int i = 0; i < 4; ++i)
#pragma unroll
        for (int j = 0; j < 4; ++j) acc[i][j] = (f32x4)(0.f);

    // prologue: tile 0 -> A0/B0, tile 1 -> A1/B1 (16 loads outstanding)
    {
        GLL16(abase + lane8, (char*)&A0[0]);
        GLL16(abase + 512 + lane8, (char*)&A0[512]);
        GLL16(abase + 1024 + lane8, (char*)&A0[1024]);
        GLL16(abase + 1536 + lane8, (char*)&A0[1536]);
        GLL16(bbase + lane8, (char*)&B0[0]);
        GLL16(bbase + 512 + lane8, (char*)&B0[512]);
        GLL16(bbase + 4096 + lane8, (char*)&B0[1024]);
        GLL16(bbase + 4608 + lane8, (char*)&B0[1536]);
        const unsigned short* as = abase + 8192;
        const unsigned short* bs = bbase + 8192;
        GLL16(as + lane8, (char*)&A1[0]);
        GLL16(as + 512 + lane8, (char*)&A1[512]);
        GLL16(as + 1024 + lane8, (char*)&A1[1024]);
        GLL16(as + 1536 + lane8, (char*)&A1[1536]);
        GLL16(bs + lane8, (char*)&B1[0]);
        GLL16(bs + 512 + lane8, (char*)&B1[512]);
        GLL16(bs + 4096 + lane8, (char*)&B1[1024]);
        GLL16(bs + 4608 + lane8, (char*)&B1[1536]);
    }

    for (int t = 0; t < NK1T; t += 2) {
        F1T(A0, B0, t + 2, 0, (t + 2) < NK1T);
        F1T(A1, B1, t + 3, (t + 1) == NK1T - 1, (t + 3) < NK1T);
    }

    // epilogue: bias + exact GELU + mult_bias -> fragment-packed act
    const float* b1e = b1 + (size_t)e * H2_;
    const float* mbe = mbias + (size_t)e * H_;
    const int colL = lane & 15, rq4 = (lane >> 4) * 4;
#pragma unroll
    for (int mi = 0; mi < 4; ++mi) {
        const int rowbase = rb * 64 + mi * 16;
        const int sg2 = e * 4 + (rowbase >> 8);
        const int m16w = (rowbase >> 4) & 15;
#pragma unroll
        for (int v = 0; v < 2; ++v) {
            const int f = fh * 32 + v * 16 + colL;
            const bool real = f < H_;
            const float bv = real ? b1e[f] : 0.f;
            const float bg = real ? b1e[H_ + f] : 0.f;
            const float mv = real ? mbe[f] : 0.f;
            const int ktf = f >> 6, k32f = (f >> 5) & 1;
            const int lhi = ((f >> 3) & 3) << 4;
            const int bb = f & 7;
            const size_t cbase = ((size_t)(sg2 * NKT2 + ktf) << 14) + (k32f << 13) + (m16w << 9);
#pragma unroll
            for (int j = 0; j < 4; ++j) {
                float a = 0.f;
                if (real) {
                    const float val = acc[mi][v][j] + bv;
                    const float gt  = acc[mi][2 + v][j] + bg;
                    a = 0.5f * gt * (1.f + erff(gt * 0.70710678118654752f)) * val * mv;
                }
                actP[cbase + (size_t)((lhi | (rq4 + j)) * 8 + bb)] = f2bf(a);
            }
        }
    }
}

// ---------------- GEMM2: 1-wave blocks, barrier-free; wave tile 64r x 64d, BK=32 ----------------
#define F2T(ABUF, BBUF, KTN, LAST, PF)                                        \
    do {                                                                      \
        if (LAST) { VMCNT0(); } else { VMW8(); }                              \
        SCHEDB();                                                             \
        short8 a0, a1, a2, a3, b0, b1, b2, b3;                                \
        a0 = *(const short8*)&ABUF[lane8];                                    \
        a1 = *(const short8*)&ABUF[512 + lane8];                              \
        a2 = *(const short8*)&ABUF[1024 + lane8];                             \
        a3 = *(const short8*)&ABUF[1536 + lane8];                             \
        b0 = *(const short8*)&BBUF[lane8];                                    \
        b1 = *(const short8*)&BBUF[512 + lane8];                              \
        b2 = *(const short8*)&BBUF[1024 + lane8];                             \
        b3 = *(const short8*)&BBUF[1536 + lane8];                             \
        LGKM0(); SCHEDB();                                                    \
        if (PF) {                                                             \
            const unsigned short* as = abase + AOFF(KTN);                     \
            const unsigned short* bs = bbase + BOFF2(KTN);                    \
            GLL16(as + lane8, (char*)&ABUF[0]);                               \
            GLL16(as + 512 + lane8, (char*)&ABUF[512]);                       \
            GLL16(as + 1024 + lane8, (char*)&ABUF[1024]);                     \
            GLL16(as + 1536 + lane8, (char*)&ABUF[1536]);                     \
            GLL16(bs + lane8, (char*)&BBUF[0]);                               \
            GLL16(bs + 512 + lane8, (char*)&BBUF[512]);                       \
            GLL16(bs + 1024 + lane8, (char*)&BBUF[1024]);                     \
            GLL16(bs + 1536 + lane8, (char*)&BBUF[1536]);                     \
        }                                                                     \
        __builtin_amdgcn_s_setprio(1);                                        \
        acc[0][0]=MFMA16(a0,b0,acc[0][0]); acc[0][1]=MFMA16(a0,b1,acc[0][1]); \
        acc[0][2]=MFMA16(a0,b2,acc[0][2]); acc[0][3]=MFMA16(a0,b3,acc[0][3]); \
        acc[1][0]=MFMA16(a1,b0,acc[1][0]); acc[1][1]=MFMA16(a1,b1,acc[1][1]); \
        acc[1][2]=MFMA16(a1,b2,acc[1][2]); acc[1][3]=MFMA16(a1,b3,acc[1][3]); \
        acc[2][0]=MFMA16(a2,b0,acc[2][0]); acc[2][1]=MFMA16(a2,b1,acc[2][1]); \
        acc[2][2]=MFMA16(a2,b2,acc[2][2]); acc[2][3]=MFMA16(a2,b3,acc[2][3]); \
        acc[3][0]=MFMA16(a3,b0,acc[3][0]); acc[3][1]=MFMA16(a3,b1,acc[3][1]); \
        acc[3][2]=MFMA16(a3,b2,acc[3][2]); acc[3][3]=MFMA16(a3,b3,acc[3][3]); \
        __builtin_amdgcn_s_setprio(0);                                        \
    } while (0)

__global__ __launch_bounds__(64) void k_ffn2(const unsigned short* __restrict__ actP,
                                             const unsigned short* __restrict__ w2p,
                                             const float* __restrict__ b2,
                                             unsigned short* __restrict__ oute) {
    const int wg = blockIdx.x;               // 2048 = 8 XCD * 256
    const int e = wg & 7;
    const int rem = wg >> 3;                 // 0..255
    const int db = rem >> 4;                 // 0..15 (64-d blocks; 16 rb share B panel)
    const int rb = rem & 15;                 // 0..15 (64-row blocks)
    const int sgrp = e * 4 + (rb >> 2);
    const int m16b = (rb & 3) * 4;
    const int n16b = (db & 1) * 4;

    __shared__ unsigned short A0[2048];
    __shared__ unsigned short B0[2048];
    __shared__ unsigned short A1[2048];
    __shared__ unsigned short B1[2048];      // 16 KB

    const int lane = threadIdx.x;
    const int lane8 = lane * 8;

    const unsigned short* abase = actP + ((size_t)(sgrp * NKT2) << 14) + m16b * 512;
    const unsigned short* bbase = w2p + ((size_t)((e * 8 + (db >> 1)) * NKT2) << 13) + n16b * 512;

    f32x4 acc[4][4];
#pragma unroll
    for (int i = 0; i < 4; ++i)
#pragma unroll
        for (int j = 0; j < 4; ++j) acc[i][j] = (f32x4)(0.f);

    // prologue: tile 0 -> A0/B0, tile 1 -> A1/B1
    {
        GLL16(abase + lane8, (char*)&A0[0]);
        GLL16(abase + 512 + lane8, (char*)&A0[512]);
        GLL16(abase + 1024 + lane8, (char*)&A0[1024]);
        GLL16(abase + 1536 + lane8, (char*)&A0[1536]);
        GLL16(bbase + lane8, (char*)&B0[0]);
        GLL16(bbase + 512 + lane8, (char*)&B0[512]);
        GLL16(bbase + 1024 + lane8, (char*)&B0[1024]);
        GLL16(bbase + 1536 + lane8, (char*)&B0[1536]);
        const unsigned short* as = abase + 8192;
        const unsigned short* bs = bbase + 4096;
        GLL16(as + lane8, (char*)&A1[0]);
        GLL16(as + 512 + lane8, (char*)&A1[512]);
        GLL16(as + 1024 + lane8, (char*)&A1[1024]);
        GLL16(as + 1536 + lane8, (char*)&A1[1536]);
        GLL16(bs + lane8, (char*)&B1[0]);
        GLL16(bs + 512 + lane8, (char*)&B1[512]);
        GLL16(bs + 1024 + lane8, (char*)&B1[1024]);
        GLL16(bs + 1536 + lane8, (char*)&B1[1536]);
    }

    for (int t = 0; t < NK2T; t += 2) {
        F2T(A0, B0, t + 2, 0, (t + 2) < NK2T);
        F2T(A1, B1, t + 3, (t + 1) == NK2T - 1, (t + 3) < NK2T);
    }

    const float* b2e = b2 + (size_t)e * D_;
    const int colL = lane & 15, rq4 = (lane >> 4) * 4;
#pragma unroll
    for (int mi = 0; mi < 4; ++mi) {
#pragma unroll
        for (int nf = 0; nf < 4; ++nf) {
            const int d = db * 64 + nf * 16 + colL;
            const float bb2 = b2e[d];
#pragma unroll
            for (int j = 0; j < 4; ++j) {
                const int R = rb * 64 + mi * 16 + rq4 + j;
                oute[((size_t)(e * 1024 + R) << 10) + d] = f2bf(acc[mi][nf][j] + bb2);
            }
        }
    }
}

// ---------------- combine (bf16 oute) ----------------
__global__ __launch_bounds__(256) void k_comb(const unsigned short* __restrict__ oute,
                                              const int* __restrict__ sot,
                                              const float* __restrict__ tokG,
                                              float* __restrict__ out) {
    const int bt = blockIdx.x;
    const int t = threadIdx.x;
    const int s0 = sot[bt], s1 = sot[NTOK + bt];
    const float g0 = tokG[bt], g1 = tokG[NTOK + bt];
    float r0 = 0.f, r1 = 0.f, r2 = 0.f, r3 = 0.f;
    if (s0 >= 0) {
        const ushort4 v = *reinterpret_cast<const ushort4*>(oute + ((size_t)s0 << 10) + t * 4);
        r0 += g0 * bf2f(v.x); r1 += g0 * bf2f(v.y); r2 += g0 * bf2f(v.z); r3 += g0 * bf2f(v.w);
    }
    if (s1 >= 0) {
        const ushort4 v = *reinterpret_cast<const ushort4*>(oute + ((size_t)s1 << 10) + t * 4);
        r0 += g1 * bf2f(v.x); r1 += g1 * bf2f(v.y); r2 += g1 * bf2f(v.z); r3 += g1 * bf2f(v.w);
    }
    float4 o; o.x = r0; o.y = r1; o.z = r2; o.w = r3;
    *reinterpret_cast<float4*>(out + ((size_t)bt << 10) + t * 4) = o;
}

extern "C" void kernel_launch(void* const* d_in, const int* in_sizes, int n_in,
                              void* d_out, int out_size, void* d_ws, size_t ws_size,
                              hipStream_t stream) {
    const float* x     = (const float*)d_in[0];
    const float* route = (const float*)d_in[1];
    const float* gw    = (const float*)d_in[2];
    const float* w1    = (const float*)d_in[3];
    const float* b1    = (const float*)d_in[4];
    const float* mb    = (const float*)d_in[5];
    const float* w2    = (const float*)d_in[6];
    const float* b2    = (const float*)d_in[7];
    float* out = (float*)d_out;

    char* ws = (char*)d_ws;
    int*   tokE = (int*)(ws + 0);
    float* tokG = (float*)(ws + 32768);
    int*   tokR = (int*)(ws + 65536);
    int*   sot  = (int*)(ws + 81920);
    int*   tos  = (int*)(ws + 114688);
    unsigned short* xeP  = (unsigned short*)(ws + 147456);      // 16.78 MB, end 16,924,672
    unsigned short* actP = (unsigned short*)(ws + 16924672);    // 45.09 MB, end 62,013,440
    unsigned short* w1p  = (unsigned short*)(ws + 62013440);    // 92.27 MB, end 154,288,128 (dead after ffn1)
    unsigned short* w2p  = (unsigned short*)(ws + 62013440);    // 45.09 MB overlay (written after ffn1)
    unsigned short* oute = (unsigned short*)(ws + 107102208);   // 16.78 MB overlay, end 123,879,424

    hipMemsetAsync(sot, 0xFF, 65536, stream);  // sot + tos -> -1

    k_cvt1<<<dim3(NFG, NKT1, 8), 256, 0, stream>>>(w1, w1p);
    k_gate<<<NTOK / 4, 256, 0, stream>>>(x, route, gw, tokE, tokG, tokR);
    k_pos<<<E_ * B_, 256, 0, stream>>>(tokE, tokG, tokR, sot, tos);
    k_disp<<<NSLOT / 2, 256, 0, stream>>>(x, tos, xeP);
    k_ffn1<<<11008, 64, 0, stream>>>(xeP, w1p, b1, mb, actP);
    k_cvt2<<<dim3(NKT2, 8, 8), 256, 0, stream>>>(w2, w2p);      // after ffn1: w2p overlays w1p
    k_ffn2<<<2048, 64, 0, stream>>>(actP, w2p, b2, oute);
    k_comb<<<NTOK, 256, 0, stream>>>(oute, sot, tokG, out);
}

// Round 12
// 302.321 us; speedup vs baseline: 1.1546x; 1.1546x over previous
//
#include <hip/hip_runtime.h>
#include <hip/hip_bf16.h>
#include <math.h>

#define B_ 4
#define N_ 1024
#define D_ 1024
#define E_ 8
#define H_ 2730
#define H2_ 5460
#define CAP_ 256
#define NTOK 4096
#define NSLOT 8192
#define NKT1 16      // K-tiles for GEMM1 (K=1024, BK=64)
#define NKT2 43      // K-tiles for GEMM2 (K=2752, BK=64)
#define NFG 22       // 128-wide f-col groups (pad 2816)

typedef __attribute__((ext_vector_type(8))) short short8;
typedef __attribute__((ext_vector_type(4))) float f32x4;

__device__ __forceinline__ unsigned short f2bf(float f) {
    __hip_bfloat16 h = __float2bfloat16(f);
    return *reinterpret_cast<unsigned short*>(&h);
}
__device__ __forceinline__ float bf2f(unsigned short u) {
    unsigned x = ((unsigned)u) << 16;
    union { unsigned u; float f; } c; c.u = x; return c.f;
}

// async global(16B/lane) -> LDS (wave-uniform base + lane*16)
#define GLL16(g, l)                                                          \
    __builtin_amdgcn_global_load_lds(                                        \
        (const __attribute__((address_space(1))) void*)(g),                  \
        (__attribute__((address_space(3))) void*)(l), 16, 0, 0)

#define VMCNT4() asm volatile("s_waitcnt vmcnt(4)" ::: "memory")
#define VMCNT3() asm volatile("s_waitcnt vmcnt(3)" ::: "memory")
#define VMCNT0() asm volatile("s_waitcnt vmcnt(0)" ::: "memory")
#define SBAR()   __builtin_amdgcn_s_barrier()
#define SCHEDB() __builtin_amdgcn_sched_barrier(0)
#define MFMA16(a, b, c) __builtin_amdgcn_mfma_f32_16x16x32_bf16((a), (b), (c), 0, 0, 0)

// ============ fragment-packed layouts ============
// A chunk (per (sgrp,kt), 16384 ush = 32KB): off = k32*8192 + m16*512 + lane*8 + b
// B1 chunk (per (e,fg,kt), 16384 ush): off = k32*8192 + n16*512 + lane*8 + b ; n16 0..7 val, 8..15 gate
// B2 chunk (per (e,nt,kt), 8192 ush):  off = k32*4096 + n16*512 + lane*8 + b

// ---------------- cvt1: w1 f32 -> fragment-packed bf16 (LDS-transpose, float4 loads) ----------------
__global__ __launch_bounds__(256) void k_cvt1(const float* __restrict__ w1,
                                              unsigned short* __restrict__ w1p) {
    const int fg = blockIdx.x;   // 0..21
    const int kt = blockIdx.y;   // 0..15
    const int e  = blockIdx.z;
    const float* w1e = w1 + (size_t)e * D_ * H2_;
    unsigned short* dst = w1p + (((size_t)((e * NFG + fg) * NKT1 + kt)) << 14);
    __shared__ unsigned short tile[128][66];   // padded: reads ~2-way, writes ~8-way
    const int t = threadIdx.x;
    const int fl4 = (t & 31) * 4;   // local f 0..124
    const int kr  = t >> 5;         // 0..7
    const int fbase = fg * 128;

    for (int m = 0; m < 2; ++m) {   // 0 = val, 1 = gate
        if (m) __syncthreads();
        const int c0 = m * H_;
        // ---- load: 64 k-rows x 128 f-cols, float4 along f (coalesced) ----
#pragma unroll
        for (int ii = 0; ii < 8; ++ii) {
            const int kl = ii * 8 + kr;
            const float* src = w1e + (size_t)(kt * 64 + kl) * H2_ + c0 + fbase + fl4;
            float v0, v1, v2, v3;
            if (fbase + fl4 + 3 < H_) {
                const float4 v = *reinterpret_cast<const float4*>(src);
                v0 = v.x; v1 = v.y; v2 = v.z; v3 = v.w;
            } else {
                v0 = (fbase + fl4 + 0 < H_) ? src[0] : 0.f;
                v1 = (fbase + fl4 + 1 < H_) ? src[1] : 0.f;
                v2 = (fbase + fl4 + 2 < H_) ? src[2] : 0.f;
                v3 = (fbase + fl4 + 3 < H_) ? src[3] : 0.f;
            }
            tile[fl4 + 0][kl] = f2bf(v0);
            tile[fl4 + 1][kl] = f2bf(v1);
            tile[fl4 + 2][kl] = f2bf(v2);
            tile[fl4 + 3][kl] = f2bf(v3);
        }
        __syncthreads();
        // ---- pack: 1024 octets -> fragment layout, 16B coalesced stores ----
#pragma unroll
        for (int i = 0; i < 4; ++i) {
            const int o = i * 256 + t;            // 0..1023
            const int k32  = o >> 9;
            const int flhi = (o >> 6) & 7;
            const int lane = o & 63;
            const int kq   = lane >> 4;
            const int fl   = flhi * 16 + (lane & 15);
            const int kb   = k32 * 32 + kq * 8;   // even, so u32 reads are 4B-aligned
            const unsigned* rp = reinterpret_cast<const unsigned*>(&tile[fl][kb]);
            uint4 q; q.x = rp[0]; q.y = rp[1]; q.z = rp[2]; q.w = rp[3];
            const size_t off = ((size_t)k32 << 13) + (size_t)(m * 8 + flhi) * 512 + (size_t)lane * 8;
            *reinterpret_cast<uint4*>(dst + off) = q;
        }
    }
}

// ---------------- cvt2: w2 f32 -> fragment-packed bf16 (LDS-transpose, float4 loads) ----------------
__global__ __launch_bounds__(256) void k_cvt2(const float* __restrict__ w2,
                                              unsigned short* __restrict__ w2p) {
    const int kt = blockIdx.x;   // 0..42
    const int nt = blockIdx.y;   // 0..7
    const int e  = blockIdx.z;
    const float* w2e = w2 + (size_t)e * H_ * D_;
    unsigned short* dst = w2p + (((size_t)((e * 8 + nt) * NKT2 + kt)) << 13);
    __shared__ unsigned short tile[128][66];
    const int t = threadIdx.x;
    const int d4 = (t & 31) * 4;    // local d 0..124
    const int fr = t >> 5;          // 0..7

    // ---- load: 64 f-rows x 128 d-cols, float4 along d (coalesced) ----
#pragma unroll
    for (int ii = 0; ii < 8; ++ii) {
        const int fl = ii * 8 + fr;
        const int f = kt * 64 + fl;
        float v0 = 0.f, v1 = 0.f, v2 = 0.f, v3 = 0.f;
        if (f < H_) {
            const float4 v = *reinterpret_cast<const float4*>(w2e + (size_t)f * D_ + nt * 128 + d4);
            v0 = v.x; v1 = v.y; v2 = v.z; v3 = v.w;
        }
        tile[d4 + 0][fl] = f2bf(v0);
        tile[d4 + 1][fl] = f2bf(v1);
        tile[d4 + 2][fl] = f2bf(v2);
        tile[d4 + 3][fl] = f2bf(v3);
    }
    __syncthreads();
    // ---- pack: 1024 octets ----
#pragma unroll
    for (int i = 0; i < 4; ++i) {
        const int o = i * 256 + t;             // 0..1023
        const int k32 = o >> 9;
        const int dhi = (o >> 6) & 7;
        const int lane = o & 63;
        const int kq = lane >> 4;
        const int dl = dhi * 16 + (lane & 15);
        const int fb = k32 * 32 + kq * 8;
        const unsigned* rp = reinterpret_cast<const unsigned*>(&tile[dl][fb]);
        uint4 q; q.x = rp[0]; q.y = rp[1]; q.z = rp[2]; q.w = rp[3];
        const size_t off = ((size_t)k32 << 12) + (size_t)dhi * 512 + (size_t)lane * 8;
        *reinterpret_cast<uint4*>(dst + off) = q;
    }
}

// ---------------- gating ----------------
__global__ __launch_bounds__(256) void k_gate(const float* __restrict__ x,
                                              const float* __restrict__ route,
                                              const float* __restrict__ gw,
                                              int* __restrict__ tokE,
                                              float* __restrict__ tokG,
                                              int* __restrict__ tokR) {
    const int wave = threadIdx.x >> 6, lane = threadIdx.x & 63;
    const int t = blockIdx.x * 4 + wave;
    float acc[E_];
#pragma unroll
    for (int e = 0; e < E_; ++e) acc[e] = 0.f;
    const float* xr = x + (size_t)t * D_;
    for (int d = lane; d < D_; d += 64) {
        float xv = xr[d];
        const float* g = gw + d * E_;
#pragma unroll
        for (int e = 0; e < E_; ++e) acc[e] = fmaf(xv, g[e], acc[e]);
    }
#pragma unroll
    for (int e = 0; e < E_; ++e) {
#pragma unroll
        for (int off = 32; off; off >>= 1) acc[e] += __shfl_xor(acc[e], off);
    }
    if (lane == 0) {
        float m = acc[0];
#pragma unroll
        for (int e = 1; e < E_; ++e) m = fmaxf(m, acc[e]);
        float p[E_]; float s = 0.f;
#pragma unroll
        for (int e = 0; e < E_; ++e) { p[e] = expf(acc[e] - m); s += p[e]; }
        int i0 = 0; float v0 = p[0];
#pragma unroll
        for (int e = 1; e < E_; ++e) if (p[e] > v0) { v0 = p[e]; i0 = e; }
        int i1 = (i0 == 0) ? 1 : 0; float v1 = p[i1];
#pragma unroll
        for (int e = 0; e < E_; ++e) if (e != i0 && p[e] > v1) { v1 = p[e]; i1 = e; }
        float p0 = v0 / s, p1 = v1 / s;
        float denom = fmaxf(p0 + p1, 1e-9f);
        float g0 = p0 / denom, g1 = p1 / denom;
        int r1 = route[NTOK + t] < (g1 / 0.2f);
        tokE[t] = i0; tokE[NTOK + t] = i1;
        tokG[t] = g0; tokG[NTOK + t] = g1;
        tokR[t] = r1;
    }
}

// ---------------- positions ----------------
__global__ __launch_bounds__(256) void k_pos(const int* __restrict__ tokE,
                                             const float* __restrict__ tokG,
                                             const int* __restrict__ tokR,
                                             int* __restrict__ sot,
                                             int* __restrict__ tos) {
    const int e = blockIdx.x & 7, b = blockIdx.x >> 3;
    const int t = threadIdx.x;
    __shared__ int sc[256];
    const int base_bt = b * N_ + t * 4;
    int m0[4], m1[4];
    int c0 = 0, c1 = 0;
#pragma unroll
    for (int i = 0; i < 4; ++i) {
        int bt = base_bt + i;
        m0[i] = (tokE[bt] == e) ? 1 : 0;
        m1[i] = ((tokE[NTOK + bt] == e) && tokR[bt]) ? 1 : 0;
        c0 += m0[i]; c1 += m1[i];
    }
    int packed = c0 | (c1 << 16);
    sc[t] = packed;
    __syncthreads();
    for (int off = 1; off < 256; off <<= 1) {
        int v = (t >= off) ? sc[t - off] : 0;
        __syncthreads();
        sc[t] += v;
        __syncthreads();
    }
    int incl = sc[t];
    int total = sc[255];
    int excl = incl - packed;
    int base0 = excl & 0xffff;
    int base1 = excl >> 16;
    int kept0 = min(total & 0xffff, CAP_);
#pragma unroll
    for (int i = 0; i < 4; ++i) {
        int bt = base_bt + i;
        if (m0[i]) {
            int pos = base0++;
            if (pos < CAP_ && tokG[bt] > 0.f) {
                int s = ((e * B_ + b) << 8) + pos;
                sot[bt] = s;
                tos[s] = bt;
            }
        }
        if (m1[i]) {
            int pos = (base1++) + kept0;
            if (pos < CAP_ && tokG[NTOK + bt] > 0.f) {
                int s = ((e * B_ + b) << 8) + pos;
                sot[NTOK + bt] = s;
                tos[s] = bt;
            }
        }
    }
}

// ---------------- dispatch: gather x rows -> fragment-packed bf16 xe ----------------
__global__ __launch_bounds__(256) void k_disp(const float* __restrict__ x,
                                              const int* __restrict__ tos,
                                              unsigned short* __restrict__ xeP) {
    const int t = threadIdx.x;
    const int s = blockIdx.x * 2 + (t >> 7);
    const int q = t & 127;                   // k-octet index
    const int bt = tos[s];
    const int kt = q >> 3, k32 = (q >> 2) & 1, kq = q & 3;
    const int lane = (kq << 4) | (s & 15);
    const int m16 = (s >> 4) & 15;
    const int sgrp = s >> 8;
    unsigned short* dst = xeP + (((size_t)(sgrp * NKT1 + kt)) << 14) + (k32 << 13) + (m16 << 9) + lane * 8;
    ushort4 r0 = {0, 0, 0, 0}, r1 = {0, 0, 0, 0};
    if (bt >= 0) {
        const float4 v0 = *reinterpret_cast<const float4*>(x + ((size_t)bt << 10) + q * 8);
        const float4 v1 = *reinterpret_cast<const float4*>(x + ((size_t)bt << 10) + q * 8 + 4);
        r0.x = f2bf(v0.x); r0.y = f2bf(v0.y); r0.z = f2bf(v0.z); r0.w = f2bf(v0.w);
        r1.x = f2bf(v1.x); r1.y = f2bf(v1.y); r1.z = f2bf(v1.z); r1.w = f2bf(v1.w);
    }
    *reinterpret_cast<ushort4*>(dst) = r0;
    *reinterpret_cast<ushort4*>(dst + 4) = r1;
}

// ---------------- GEMM1 + GEGLU: distinct-buffer dbuf, counted-vmcnt (r5 best) ----------------
#define LDF(BUF, idx) (*reinterpret_cast<const short8*>(&BUF[(idx) * 512 + lane8]))

#define FFN1_MM03(AF0, AF1, AF2, AF3)                                         \
    do {                                                                      \
        acc[0][0]=MFMA16(AF0,bf0,acc[0][0]); acc[0][1]=MFMA16(AF0,bf1,acc[0][1]); \
        acc[0][2]=MFMA16(AF0,bf2,acc[0][2]); acc[0][3]=MFMA16(AF0,bf3,acc[0][3]); \
        acc[1][0]=MFMA16(AF1,bf0,acc[1][0]); acc[1][1]=MFMA16(AF1,bf1,acc[1][1]); \
        acc[1][2]=MFMA16(AF1,bf2,acc[1][2]); acc[1][3]=MFMA16(AF1,bf3,acc[1][3]); \
        acc[2][0]=MFMA16(AF2,bf0,acc[2][0]); acc[2][1]=MFMA16(AF2,bf1,acc[2][1]); \
        acc[2][2]=MFMA16(AF2,bf2,acc[2][2]); acc[2][3]=MFMA16(AF2,bf3,acc[2][3]); \
        acc[3][0]=MFMA16(AF3,bf0,acc[3][0]); acc[3][1]=MFMA16(AF3,bf1,acc[3][1]); \
        acc[3][2]=MFMA16(AF3,bf2,acc[3][2]); acc[3][3]=MFMA16(AF3,bf3,acc[3][3]); \
    } while (0)
#define FFN1_MM47(AF0, AF1, AF2, AF3)                                         \
    do {                                                                      \
        acc[4][0]=MFMA16(AF0,bf0,acc[4][0]); acc[4][1]=MFMA16(AF0,bf1,acc[4][1]); \
        acc[4][2]=MFMA16(AF0,bf2,acc[4][2]); acc[4][3]=MFMA16(AF0,bf3,acc[4][3]); \
        acc[5][0]=MFMA16(AF1,bf0,acc[5][0]); acc[5][1]=MFMA16(AF1,bf1,acc[5][1]); \
        acc[5][2]=MFMA16(AF1,bf2,acc[5][2]); acc[5][3]=MFMA16(AF1,bf3,acc[5][3]); \
        acc[6][0]=MFMA16(AF2,bf0,acc[6][0]); acc[6][1]=MFMA16(AF2,bf1,acc[6][1]); \
        acc[6][2]=MFMA16(AF2,bf2,acc[6][2]); acc[6][3]=MFMA16(AF2,bf3,acc[6][3]); \
        acc[7][0]=MFMA16(AF3,bf0,acc[7][0]); acc[7][1]=MFMA16(AF3,bf1,acc[7][1]); \
        acc[7][2]=MFMA16(AF3,bf2,acc[7][2]); acc[7][3]=MFMA16(AF3,bf3,acc[7][3]); \
    } while (0)

#define FFN1_KT(ARD, BRD, AWR, BWR, KTN, PF)                                  \
    do {                                                                      \
        const unsigned short* asn = abase + ((size_t)(KTN) << 14);            \
        const unsigned short* bsn = bbase + ((size_t)(KTN) << 14);            \
        short8 af0, af1, af2, af3, bf0, bf1, bf2, bf3;                        \
        SCHEDB(); VMCNT4(); SBAR(); SCHEDB();                                 \
        if (PF) {                                                             \
            GLL16(asn + woff + lane8, (char*)&AWR[woff]);                     \
            GLL16(asn + woff + 512 + lane8, (char*)&AWR[woff + 512]);         \
        }                                                                     \
        bf0 = LDF(BRD, bn0); bf1 = LDF(BRD, bn0 + 1);                         \
        bf2 = LDF(BRD, bn0 + 8); bf3 = LDF(BRD, bn0 + 9);                     \
        af0 = LDF(ARD, am0 + 0); af1 = LDF(ARD, am0 + 1);                     \
        af2 = LDF(ARD, am0 + 2); af3 = LDF(ARD, am0 + 3);                     \
        __builtin_amdgcn_s_setprio(1);                                        \
        FFN1_MM03(af0, af1, af2, af3);                                        \
        __builtin_amdgcn_s_setprio(0);                                        \
        if (PF) {                                                             \
            GLL16(bsn + woff + lane8, (char*)&BWR[woff]);                     \
            GLL16(bsn + woff + 512 + lane8, (char*)&BWR[woff + 512]);         \
        }                                                                     \
        af0 = LDF(ARD, am0 + 4); af1 = LDF(ARD, am0 + 5);                     \
        af2 = LDF(ARD, am0 + 6); af3 = LDF(ARD, am0 + 7);                     \
        __builtin_amdgcn_s_setprio(1);                                        \
        FFN1_MM47(af0, af1, af2, af3);                                        \
        __builtin_amdgcn_s_setprio(0);                                        \
        SCHEDB(); if (PF) { VMCNT4(); } else { VMCNT0(); } SBAR(); SCHEDB();  \
        if (PF) {                                                             \
            GLL16(asn + 8192 + woff + lane8, (char*)&AWR[8192 + woff]);       \
            GLL16(asn + 8192 + woff + 512 + lane8, (char*)&AWR[8192 + woff + 512]); \
        }                                                                     \
        bf0 = LDF(BRD, 16 + bn0); bf1 = LDF(BRD, 16 + bn0 + 1);               \
        bf2 = LDF(BRD, 16 + bn0 + 8); bf3 = LDF(BRD, 16 + bn0 + 9);           \
        af0 = LDF(ARD, 16 + am0 + 0); af1 = LDF(ARD, 16 + am0 + 1);           \
        af2 = LDF(ARD, 16 + am0 + 2); af3 = LDF(ARD, 16 + am0 + 3);           \
        __builtin_amdgcn_s_setprio(1);                                        \
        FFN1_MM03(af0, af1, af2, af3);                                        \
        __builtin_amdgcn_s_setprio(0);                                        \
        if (PF) {                                                             \
            GLL16(bsn + 8192 + woff + lane8, (char*)&BWR[8192 + woff]);       \
            GLL16(bsn + 8192 + woff + 512 + lane8, (char*)&BWR[8192 + woff + 512]); \
        }                                                                     \
        af0 = LDF(ARD, 16 + am0 + 4); af1 = LDF(ARD, 16 + am0 + 5);           \
        af2 = LDF(ARD, 16 + am0 + 6); af3 = LDF(ARD, 16 + am0 + 7);           \
        __builtin_amdgcn_s_setprio(1);                                        \
        FFN1_MM47(af0, af1, af2, af3);                                        \
        __builtin_amdgcn_s_setprio(0);                                        \
    } while (0)

__global__ __launch_bounds__(512) void k_ffn1(const unsigned short* __restrict__ xeP,
                                              const unsigned short* __restrict__ w1p,
                                              const float* __restrict__ b1,
                                              const float* __restrict__ mbias,
                                              unsigned short* __restrict__ actP) {
    const int wg = blockIdx.x;               // 704 = 8 XCD * 88
    const int e = wg & 7;
    const int rem = wg >> 3;
    const int fg = rem >> 2;                 // 0..21
    const int rt = rem & 3;                  // 0..3
    const int sgrp = e * 4 + rt;

    __shared__ unsigned short Ab0[16384];
    __shared__ unsigned short Bb0[16384];
    __shared__ unsigned short Ab1[16384];
    __shared__ unsigned short Bb1[16384];

    const int tid = threadIdx.x, lane = tid & 63, w = tid >> 6;
    const int wm = w >> 2, wn = w & 3;
    const int lane8 = lane * 8;
    const int woff = w * 1024;
    const int am0 = wm * 8, bn0 = wn * 2;

    const unsigned short* abase = xeP + ((size_t)(sgrp * NKT1) << 14);
    const unsigned short* bbase = w1p + ((size_t)((e * NFG + fg) * NKT1) << 14);

    f32x4 acc[8][4];
#pragma unroll
    for (int i = 0; i < 8; ++i)
#pragma unroll
        for (int j = 0; j < 4; ++j) acc[i][j] = (f32x4)(0.f);

    // prologue: tile 0 -> buf0, issue order {A-h0, B-h0, A-h1, B-h1}
    GLL16(abase + woff + lane8, (char*)&Ab0[woff]);
    GLL16(abase + woff + 512 + lane8, (char*)&Ab0[woff + 512]);
    GLL16(bbase + woff + lane8, (char*)&Bb0[woff]);
    GLL16(bbase + woff + 512 + lane8, (char*)&Bb0[woff + 512]);
    GLL16(abase + 8192 + woff + lane8, (char*)&Ab0[8192 + woff]);
    GLL16(abase + 8192 + woff + 512 + lane8, (char*)&Ab0[8192 + woff + 512]);
    GLL16(bbase + 8192 + woff + lane8, (char*)&Bb0[8192 + woff]);
    GLL16(bbase + 8192 + woff + 512 + lane8, (char*)&Bb0[8192 + woff + 512]);

    for (int kt = 0; kt < NKT1; kt += 2) {
        FFN1_KT(Ab0, Bb0, Ab1, Bb1, kt + 1, 1);
        FFN1_KT(Ab1, Bb1, Ab0, Bb0, kt + 2, (kt + 2) < NKT1);
    }

    // epilogue: bias + exact GELU + mult_bias -> fragment-packed act
    const float* b1e = b1 + (size_t)e * H2_;
    const float* mbe = mbias + (size_t)e * H_;
    const int colL = lane & 15, rq4 = (lane >> 4) * 4;
#pragma unroll
    for (int mi = 0; mi < 8; ++mi) {
        const int Rl = wm * 128 + mi * 16 + rq4;
#pragma unroll
        for (int vi = 0; vi < 2; ++vi) {
            const int f = fg * 128 + wn * 32 + vi * 16 + colL;
            if (f >= NKT2 * 64) continue;
            const bool real = f < H_;
            const float bv = real ? b1e[f] : 0.f;
            const float bg = real ? b1e[H_ + f] : 0.f;
            const float mv = real ? mbe[f] : 0.f;
            const int ktf = f >> 6, k32f = (f >> 5) & 1;
            const int lhi = ((f >> 3) & 3) << 4;
            const int bb = f & 7;
            const size_t cbase = ((size_t)(sgrp * NKT2 + ktf) << 14) + (k32f << 13);
#pragma unroll
            for (int j = 0; j < 4; ++j) {
                const int R = Rl + j;
                float a = 0.f;
                if (real) {
                    const float val = acc[mi][vi][j] + bv;
                    const float gt  = acc[mi][2 + vi][j] + bg;
                    a = 0.5f * gt * (1.f + erff(gt * 0.70710678118654752f)) * val * mv;
                }
                actP[cbase + ((R >> 4) << 9) + (size_t)((lhi | (R & 15)) * 8 + bb)] = f2bf(a);
            }
        }
    }
}

// ---------------- GEMM2: distinct-buffer dbuf, counted-vmcnt (r5 best) ----------------
#define FFN2_MM03(AF0, AF1, AF2, AF3)                                         \
    do {                                                                      \
        acc[0][0]=MFMA16(AF0,bf0,acc[0][0]); acc[0][1]=MFMA16(AF0,bf1,acc[0][1]); \
        acc[1][0]=MFMA16(AF1,bf0,acc[1][0]); acc[1][1]=MFMA16(AF1,bf1,acc[1][1]); \
        acc[2][0]=MFMA16(AF2,bf0,acc[2][0]); acc[2][1]=MFMA16(AF2,bf1,acc[2][1]); \
        acc[3][0]=MFMA16(AF3,bf0,acc[3][0]); acc[3][1]=MFMA16(AF3,bf1,acc[3][1]); \
    } while (0)
#define FFN2_MM47(AF0, AF1, AF2, AF3)                                         \
    do {                                                                      \
        acc[4][0]=MFMA16(AF0,bf0,acc[4][0]); acc[4][1]=MFMA16(AF0,bf1,acc[4][1]); \
        acc[5][0]=MFMA16(AF1,bf0,acc[5][0]); acc[5][1]=MFMA16(AF1,bf1,acc[5][1]); \
        acc[6][0]=MFMA16(AF2,bf0,acc[6][0]); acc[6][1]=MFMA16(AF2,bf1,acc[6][1]); \
        acc[7][0]=MFMA16(AF3,bf0,acc[7][0]); acc[7][1]=MFMA16(AF3,bf1,acc[7][1]); \
    } while (0)

#define FFN2_KT(ARD, BRD, AWR, BWR, KTN, PF)                                  \
    do {                                                                      \
        const unsigned short* asn = abase + ((size_t)(KTN) << 14);            \
        const unsigned short* bsn = bbase + ((size_t)(KTN) << 13);            \
        short8 af0, af1, af2, af3, bf0, bf1;                                  \
        SCHEDB(); VMCNT3(); SBAR(); SCHEDB();                                 \
        if (PF) {                                                             \
            GLL16(asn + woff + lane8, (char*)&AWR[woff]);                     \
            GLL16(asn + woff + 512 + lane8, (char*)&AWR[woff + 512]);         \
        }                                                                     \
        bf0 = LDF(BRD, bn0); bf1 = LDF(BRD, bn0 + 1);                         \
        af0 = LDF(ARD, am0 + 0); af1 = LDF(ARD, am0 + 1);                     \
        af2 = LDF(ARD, am0 + 2); af3 = LDF(ARD, am0 + 3);                     \
        __builtin_amdgcn_s_setprio(1);                                        \
        FFN2_MM03(af0, af1, af2, af3);                                        \
        __builtin_amdgcn_s_setprio(0);                                        \
        if (PF) { GLL16(bsn + woffb + lane8, (char*)&BWR[woffb]); }           \
        af0 = LDF(ARD, am0 + 4); af1 = LDF(ARD, am0 + 5);                     \
        af2 = LDF(ARD, am0 + 6); af3 = LDF(ARD, am0 + 7);                     \
        __builtin_amdgcn_s_setprio(1);                                        \
        FFN2_MM47(af0, af1, af2, af3);                                        \
        __builtin_amdgcn_s_setprio(0);                                        \
        SCHEDB(); if (PF) { VMCNT3(); } else { VMCNT0(); } SBAR(); SCHEDB();  \
        if (PF) {                                                             \
            GLL16(asn + 8192 + woff + lane8, (char*)&AWR[8192 + woff]);       \
            GLL16(asn + 8192 + woff + 512 + lane8, (char*)&AWR[8192 + woff + 512]); \
        }                                                                     \
        bf0 = LDF(BRD, 8 + bn0); bf1 = LDF(BRD, 8 + bn0 + 1);                 \
        af0 = LDF(ARD, 16 + am0 + 0); af1 = LDF(ARD, 16 + am0 + 1);           \
        af2 = LDF(ARD, 16 + am0 + 2); af3 = LDF(ARD, 16 + am0 + 3);           \
        __builtin_amdgcn_s_setprio(1);                                        \
        FFN2_MM03(af0, af1, af2, af3);                                        \
        __builtin_amdgcn_s_setprio(0);                                        \
        if (PF) { GLL16(bsn + 4096 + woffb + lane8, (char*)&BWR[4096 + woffb]); } \
        af0 = LDF(ARD, 16 + am0 + 4); af1 = LDF(ARD, 16 + am0 + 5);           \
        af2 = LDF(ARD, 16 + am0 + 6); af3 = LDF(ARD, 16 + am0 + 7);           \
        __builtin_amdgcn_s_setprio(1);                                        \
        FFN2_MM47(af0, af1, af2, af3);                                        \
        __builtin_amdgcn_s_setprio(0);                                        \
    } while (0)

__global__ __launch_bounds__(512) void k_ffn2(const unsigned short* __restrict__ actP,
                                              const unsigned short* __restrict__ w2p,
                                              const float* __restrict__ b2,
                                              unsigned short* __restrict__ oute) {
    const int wg = blockIdx.x;               // 256 = 8 XCD * 32
    const int e = wg & 7;
    const int rem = wg >> 3;
    const int nt = rem >> 2;                 // 0..7
    const int mt = rem & 3;                  // 0..3
    const int sgrp = e * 4 + mt;

    __shared__ unsigned short Ab0[16384];
    __shared__ unsigned short Bb0[8192];
    __shared__ unsigned short Ab1[16384];
    __shared__ unsigned short Bb1[8192];

    const int tid = threadIdx.x, lane = tid & 63, w = tid >> 6;
    const int wm = w >> 2, wn = w & 3;
    const int lane8 = lane * 8;
    const int woff = w * 1024;
    const int woffb = w * 512;
    const int am0 = wm * 8, bn0 = wn * 2;

    const unsigned short* abase = actP + ((size_t)(sgrp * NKT2) << 14);
    const unsigned short* bbase = w2p + ((size_t)((e * 8 + nt) * NKT2) << 13);

    f32x4 acc[8][2];
#pragma unroll
    for (int i = 0; i < 8; ++i)
#pragma unroll
        for (int j = 0; j < 2; ++j) acc[i][j] = (f32x4)(0.f);

    // prologue: tile 0 -> buf0, issue order {A-h0(2), B-h0(1), A-h1(2), B-h1(1)}
    GLL16(abase + woff + lane8, (char*)&Ab0[woff]);
    GLL16(abase + woff + 512 + lane8, (char*)&Ab0[woff + 512]);
    GLL16(bbase + woffb + lane8, (char*)&Bb0[woffb]);
    GLL16(abase + 8192 + woff + lane8, (char*)&Ab0[8192 + woff]);
    GLL16(abase + 8192 + woff + 512 + lane8, (char*)&Ab0[8192 + woff + 512]);
    GLL16(bbase + 4096 + woffb + lane8, (char*)&Bb0[4096 + woffb]);

    for (int kt = 0; kt < NKT2 - 1; kt += 2) {
        FFN2_KT(Ab0, Bb0, Ab1, Bb1, kt + 1, 1);
        FFN2_KT(Ab1, Bb1, Ab0, Bb0, kt + 2, (kt + 2) < NKT2);
    }
    FFN2_KT(Ab0, Bb0, Ab1, Bb1, NKT2, 0);    // kt = 42 reads buf0, no prefetch

    const float* b2e = b2 + (size_t)e * D_;
    const int colL = lane & 15, rq4 = (lane >> 4) * 4;
#pragma unroll
    for (int mi = 0; mi < 8; ++mi) {
#pragma unroll
        for (int vi = 0; vi < 2; ++vi) {
            const int d = nt * 128 + wn * 32 + vi * 16 + colL;
            const float bb2 = b2e[d];
#pragma unroll
            for (int j = 0; j < 4; ++j) {
                const int R = mt * 256 + wm * 128 + mi * 16 + rq4 + j;
                oute[((size_t)(e * 1024 + R) << 10) + d] = f2bf(acc[mi][vi][j] + bb2);
            }
        }
    }
}

// ---------------- combine (bf16 oute) ----------------
__global__ __launch_bounds__(256) void k_comb(const unsigned short* __restrict__ oute,
                                              const int* __restrict__ sot,
                                              const float* __restrict__ tokG,
                                              float* __restrict__ out) {
    const int bt = blockIdx.x;
    const int t = threadIdx.x;
    const int s0 = sot[bt], s1 = sot[NTOK + bt];
    const float g0 = tokG[bt], g1 = tokG[NTOK + bt];
    float r0 = 0.f, r1 = 0.f, r2 = 0.f, r3 = 0.f;
    if (s0 >= 0) {
        const ushort4 v = *reinterpret_cast<const ushort4*>(oute + ((size_t)s0 << 10) + t * 4);
        r0 += g0 * bf2f(v.x); r1 += g0 * bf2f(v.y); r2 += g0 * bf2f(v.z); r3 += g0 * bf2f(v.w);
    }
    if (s1 >= 0) {
        const ushort4 v = *reinterpret_cast<const ushort4*>(oute + ((size_t)s1 << 10) + t * 4);
        r0 += g1 * bf2f(v.x); r1 += g1 * bf2f(v.y); r2 += g1 * bf2f(v.z); r3 += g1 * bf2f(v.w);
    }
    float4 o; o.x = r0; o.y = r1; o.z = r2; o.w = r3;
    *reinterpret_cast<float4*>(out + ((size_t)bt << 10) + t * 4) = o;
}

extern "C" void kernel_launch(void* const* d_in, const int* in_sizes, int n_in,
                              void* d_out, int out_size, void* d_ws, size_t ws_size,
                              hipStream_t stream) {
    const float* x     = (const float*)d_in[0];
    const float* route = (const float*)d_in[1];
    const float* gw    = (const float*)d_in[2];
    const float* w1    = (const float*)d_in[3];
    const float* b1    = (const float*)d_in[4];
    const float* mb    = (const float*)d_in[5];
    const float* w2    = (const float*)d_in[6];
    const float* b2    = (const float*)d_in[7];
    float* out = (float*)d_out;

    char* ws = (char*)d_ws;
    int*   tokE = (int*)(ws + 0);
    float* tokG = (float*)(ws + 32768);
    int*   tokR = (int*)(ws + 65536);
    int*   sot  = (int*)(ws + 81920);
    int*   tos  = (int*)(ws + 114688);
    unsigned short* xeP  = (unsigned short*)(ws + 147456);      // 16.78 MB, end 16,924,672
    unsigned short* actP = (unsigned short*)(ws + 16924672);    // 45.09 MB, end 62,013,440
    unsigned short* w1p  = (unsigned short*)(ws + 62013440);    // 92.27 MB, end 154,288,128 (dead after ffn1)
    unsigned short* w2p  = (unsigned short*)(ws + 62013440);    // 45.09 MB overlay (written after ffn1)
    unsigned short* oute = (unsigned short*)(ws + 107102208);   // 16.78 MB overlay, end 123,879,424

    hipMemsetAsync(sot, 0xFF, 65536, stream);  // sot + tos -> -1

    k_cvt1<<<dim3(NFG, NKT1, 8), 256, 0, stream>>>(w1, w1p);
    k_gate<<<NTOK / 4, 256, 0, stream>>>(x, route, gw, tokE, tokG, tokR);
    k_pos<<<E_ * B_, 256, 0, stream>>>(tokE, tokG, tokR, sot, tos);
    k_disp<<<NSLOT / 2, 256, 0, stream>>>(x, tos, xeP);
    k_ffn1<<<704, 512, 0, stream>>>(xeP, w1p, b1, mb, actP);
    k_cvt2<<<dim3(NKT2, 8, 8), 256, 0, stream>>>(w2, w2p);      // after ffn1: w2p overlays w1p
    k_ffn2<<<256, 512, 0, stream>>>(actP, w2p, b2, oute);
    k_comb<<<NTOK, 256, 0, stream>>>(oute, sot, tokG, out);
}